// Round 8
// baseline (98.581 us; speedup 1.0000x reference)
//
#include <hip/hip_runtime.h>
#include <hip/hip_bf16.h>

namespace {

typedef __attribute__((ext_vector_type(8))) short bh8;   // 8 bf16 = 4 VGPR MFMA A/B frag
typedef __attribute__((ext_vector_type(4))) short sh4;   // 4 bf16 (8B)
typedef __attribute__((ext_vector_type(4))) float fx4;

constexpr int Rn = 96, Cn = 64, CINn = 8, COUTn = 64;
constexpr int NPOS = 8 * 96 * 64 * 8;       // 393216 (b,r,c,g) positions
constexpr int PPG  = 8 * 96 * 64;           // 49152 (b,r,c) per g
// ws layout (bytes)
constexpr size_t FEAT_OFF = 0;                                // feat bf16x8, G-MAJOR [g][pb]: 6.29 MB
constexpr size_t FWT_OFF  = (size_t)NPOS * 16;                // FwT bf16 [g][o][r][i]: 6.29 MB
constexpr size_t CA_OFF   = FWT_OFF + (size_t)NPOS * 16;      // convA bf16 [g][co][64]: 64 KB
constexpr size_t GT_OFF   = CA_OFF + 65536;                   // gate table bf16 [g*128+o2][80]: 160 KB
constexpr size_t PART_OFF = GT_OFF + 163840;                  // partials f32 [16][32][1024]: 2 MB

__device__ inline ushort f2b(float f) {
  __hip_bfloat16 h = __float2bfloat16(f);
  return __builtin_bit_cast(ushort, h);
}
__device__ inline float b2f(ushort u) {
  return __builtin_bit_cast(float, (unsigned)u << 16);
}
// swizzled byte offset into a [16 bc][8 rr][64 i] bf16 buffer (128B rows, 16KB)
__device__ inline int swz8(int bc, int rr, int ib) {
  return (bc * 1024 + rr * 128 + ib) ^ (((rr + bc) & 7) << 4);
}

#define MFMA16(a, b, c) __builtin_amdgcn_mfma_f32_16x16x32_bf16((a), (b), (c), 0, 0, 0)

// ================= prep_k: feat pack (g-major) + FwT transpose + tables =================
__global__ __launch_bounds__(512)
void prep_k(const float* __restrict__ x, const float* __restrict__ xm,
            const float* __restrict__ Fw,
            const float* __restrict__ Gd, const float* __restrict__ bgd,
            const float* __restrict__ Gm, const float* __restrict__ bgm,
            const float* __restrict__ Gh, const float* __restrict__ bgh,
            const float* __restrict__ Wd, const float* __restrict__ bd,
            const float* __restrict__ Wm, const float* __restrict__ bm,
            ushort* __restrict__ feat, ushort* __restrict__ FwT,
            ushort* __restrict__ GT, ushort* __restrict__ cA)
{
  __shared__ float tile[64 * 97];
  const int bid = blockIdx.x, t = threadIdx.x;
  if (bid < 768) {
    const int pos = bid * 512 + t;
    const float xs = x[pos];
    const fx4 m = *(const fx4*)(xm + (size_t)pos * 4);
    bh8 o;
    o[0] = (short)f2b(xs);
    o[1] = (short)f2b(m[0]); o[2] = (short)f2b(m[1]);
    o[3] = (short)f2b(m[2]); o[4] = (short)f2b(m[3]);
    o[5] = (short)0x3F80; o[6] = 0; o[7] = 0;
    const int g = pos & 7, pb = pos >> 3;
    *(bh8*)(feat + ((size_t)g * PPG + pb) * 8) = o;
  } else if (bid < 1280) {
    const int go = bid - 768;
    const float* src = Fw + (size_t)go * 6144;
    ushort* dst = FwT + (size_t)go * 6144;
#pragma unroll
    for (int it = 0; it < 12; ++it) {
      const int idx = t + it * 512;
      tile[(idx / 96) * 97 + (idx % 96)] = src[idx];
    }
    __syncthreads();
#pragma unroll
    for (int it = 0; it < 12; ++it) {
      const int idx = t + it * 512;
      const int r = idx >> 6, i = idx & 63;
      dst[idx] = f2b(tile[i * 97 + r]);
    }
  } else if (bid < 1440) {
    const int idx = (bid - 1280) * 512 + t;   // 81920
    const int ro = idx / 80, c = idx - ro * 80;
    float v = 0.f;
    if (c < 64)       v = Gh[(size_t)ro * 64 + c];
    else if (c == 64) v = Gd[ro];
    else if (c <= 68) v = Gm[(size_t)ro * 4 + (c - 65)];
    else if (c == 69) v = bgd[ro] + bgm[ro] + bgh[ro];
    GT[idx] = f2b(v);
  } else {
    const int e = (bid - 1440) * 512 + t;     // 32768
    const int g = e >> 12, co = (e >> 6) & 63, k = e & 63;
    const int tap = k >> 3, tch = k & 7;
    float v = 0.f;
    if (tch == 0)      v = Wd[(g * 64 + co) * 8 + tap];
    else if (tch <= 4) v = Wm[((g * 64 + co) * 4 + (tch - 1)) * 8 + tap];
    else if (tch == 5 && tap == 0) v = bd[g * 64 + co] + bm[g * 64 + co];
    cA[e] = f2b(v);
  }
}

// ================= main: persistent block, 6 chunks, tables loaded once =================
__global__ __launch_bounds__(512, 4)
void fused_v7(const ushort* __restrict__ feat, const ushort* __restrict__ FwT,
              const ushort* __restrict__ cA, const ushort* __restrict__ GT,
              float* __restrict__ part)
{
  __shared__ __align__(16) char sHid[16384];   // [16bc][8rr][64i] bf16, swizzled
  __shared__ __align__(16) char sGat[16384];   // gated hid, same layout
  __shared__ float sRed[4 * 256];              // fc hf-reduce

  const int t    = threadIdx.x;
  const int lane = t & 63;
  const int w    = t >> 6;
  const int il   = lane >> 4;
  const int mr   = lane & 15;
  const int bid  = blockIdx.x;
  const int g    = bid & 7;                    // XCD-affine (512 % 8 == 0, bijective)
  const int bcT  = (bid >> 3) & 31;
  const int chh  = bid >> 8;                   // 0..1 -> rows chh*48 .. chh*48+47
  const ushort* fg = feat + (size_t)g * PPG * 8;

  // ---- conv geometry (fixed per thread): pos = w*16+mr -> (bcl, rr) ----
  const int pglob = w * 16 + mr;
  const int cbcl = pglob >> 3, crr = pglob & 7;
  const int cbcg = bcT * 16 + cbcl;
  const int cbb = cbcg >> 6, ccc = cbcg & 63;

  // ---- tables: loaded ONCE, resident all kernel ----
  bh8 aC[4][2];
  {
    const ushort* cAg = cA + g * 4096;
#pragma unroll
    for (int s = 0; s < 4; ++s)
#pragma unroll
      for (int hh = 0; hh < 2; ++hh)
        aC[s][hh] = *(const bh8*)(cAg + (s * 16 + mr) * 64 + hh * 32 + 8 * il);
  }
  const int hw = w & 1;
  bh8 gA[12];
  {
    const ushort* gtg = GT + (size_t)g * 128 * 80;
    const int xo = (il == 0) ? 64 : 72;          // il>0 lanes read the zero frag
#pragma unroll
    for (int ss = 0; ss < 2; ++ss) {
      const int s = 2 * hw + ss;
      const ushort* bs = gtg + (s * 16 + mr) * 80;
      const ushort* bt = gtg + (64 + s * 16 + mr) * 80;
      gA[ss * 6 + 0] = *(const bh8*)(bs + 8 * il);
      gA[ss * 6 + 1] = *(const bh8*)(bs + 32 + 8 * il);
      gA[ss * 6 + 2] = *(const bh8*)(bs + xo);
      gA[ss * 6 + 3] = *(const bh8*)(bt + 8 * il);
      gA[ss * 6 + 4] = *(const bh8*)(bt + 32 + 8 * il);
      gA[ss * 6 + 5] = *(const bh8*)(bt + xo);
    }
  }
  const int s4 = w & 3, hf = w >> 2;
  const ushort* fbase = FwT + ((size_t)(g * 64 + s4 * 16 + mr) * 96) * 64 + 32 * hf + 8 * il;

  fx4 facc = {0.f, 0.f, 0.f, 0.f};
  const bh8 zpad = {0, 0, 0, 0, 0, (short)0x3F80, 0, 0};

  // ---- prefetch chunk 0 conv inputs (clamped address; pad-select at use) ----
  bh8 b0, b1;
  {
    const int r0 = chh * 48;
    const int q0 = r0 + crr - 8 + il;
    const int q1 = q0 + 4;
    b0 = *(const bh8*)(fg + (size_t)((cbb * 96 + (q0 > 0 ? q0 : 0)) * 64 + ccc) * 8);
    b1 = *(const bh8*)(fg + (size_t)((cbb * 96 + (q1 > 0 ? q1 : 0)) * 64 + ccc) * 8);
  }

#pragma unroll
  for (int k = 0; k < 6; ++k) {
    const int r0 = chh * 48 + k * 8;

    // ---------- conv phase ----------
    if (k == 0 && chh == 0) {              // only chunk 0 has negative taps
      const int q0 = crr - 8 + il;
      if (q0 < 0) b0 = zpad;
      if (q0 + 4 < 0) b1 = zpad;
    }
#pragma unroll
    for (int s = 0; s < 4; ++s) {
      fx4 a = {0.f, 0.f, 0.f, 0.f};
      a = MFMA16(aC[s][0], b0, a);
      a = MFMA16(aC[s][1], b1, a);
      sh4 o4;
#pragma unroll
      for (int cc = 0; cc < 4; ++cc) o4[cc] = (short)f2b(a[cc]);
      *(sh4*)(sHid + swz8(cbcl, crr, s * 32 + il * 8)) = o4;
    }
    // prefetch next chunk's conv inputs (q >= 0 always for k>=1 rows)
    if (k < 5) {
      const int qn0 = r0 + crr + il;       // = (r0+8) + crr - 8 + il
      b0 = *(const bh8*)(fg + (size_t)((cbb * 96 + qn0) * 64 + ccc) * 8);
      b1 = *(const bh8*)(fg + (size_t)((cbb * 96 + qn0 + 4) * 64 + ccc) * 8);
    }
    __syncthreads();   // B1: sHid ready

    // ---------- gate phase: wave pair p=w>>1 owns nt {2p,2p+1}; hw owns s {2hw,2hw+1} ----------
    {
      bh8 bx[2];
#pragma unroll
      for (int nti = 0; nti < 2; ++nti) {
        const int nt = (w >> 1) * 2 + nti;
        const int pg = nt * 16 + mr;
        const int bcl = pg >> 3, rr = pg & 7;
        const int bcg = bcT * 16 + bcl;
        const int bb = bcg >> 6, cc_ = bcg & 63;
        bx[nti] = *(const bh8*)(fg + (size_t)((bb * 96 + r0 + rr) * 64 + cc_) * 8);
      }
#pragma unroll
      for (int nti = 0; nti < 2; ++nti) {
        const int nt = (w >> 1) * 2 + nti;
        const int pg = nt * 16 + mr;
        const int bcl = pg >> 3, rr = pg & 7;
        const bh8 h0 = *(const bh8*)(sHid + swz8(bcl, rr, 16 * il));
        const bh8 h1 = *(const bh8*)(sHid + swz8(bcl, rr, 64 + 16 * il));
#pragma unroll
        for (int ss = 0; ss < 2; ++ss) {
          const int s = 2 * hw + ss;
          fx4 aS = {0.f,0.f,0.f,0.f}, aT = {0.f,0.f,0.f,0.f};
          aS = MFMA16(gA[ss * 6 + 0], h0, aS);
          aS = MFMA16(gA[ss * 6 + 1], h1, aS);
          aT = MFMA16(gA[ss * 6 + 3], h0, aT);
          aT = MFMA16(gA[ss * 6 + 4], h1, aT);
          aS = MFMA16(gA[ss * 6 + 2], bx[nti], aS);
          aT = MFMA16(gA[ss * 6 + 5], bx[nti], aT);
          const sh4 h4 = *(const sh4*)(sHid + swz8(bcl, rr, s * 32 + il * 8));
          sh4 o4;
#pragma unroll
          for (int cc = 0; cc < 4; ++cc) {
            const float sig = 1.f / (1.f + __expf(-aS[cc]));
            const float th  = 1.f - 2.f / (1.f + __expf(2.f * aT[cc]));
            const float h   = fmaf(b2f((ushort)h4[cc]), sig, (1.f - sig) * th);
            o4[cc] = (short)f2b(h);
          }
          *(sh4*)(sGat + swz8(bcl, rr, s * 32 + il * 8)) = o4;
        }
      }
    }
    __syncthreads();   // B2: sGat ready (also fences sHid reuse via next B1)

    // ---------- fc phase: accumulate into facc (no barrier needed after) ----------
    {
      const ushort* fb = fbase + (size_t)r0 * 64;
#pragma unroll
      for (int f = 0; f < 8; ++f) {
        const bh8 aF = *(const bh8*)(fb + f * 64);
        const bh8 bF = *(const bh8*)(sGat + swz8(mr, f, 64 * hf + 16 * il));
        facc = MFMA16(aF, bF, facc);
      }
    }
  }

  // ---- hf-reduce + write partial (2 slices per output) ----
  if (hf == 1) {
#pragma unroll
    for (int cc = 0; cc < 4; ++cc)
      sRed[s4 * 256 + (4 * il + cc) * 16 + mr] = facc[cc];
  }
  __syncthreads();
  if (hf == 0) {
    float* pp = part + ((size_t)(chh * 8 + g) * 32 + bcT) * 1024;
#pragma unroll
    for (int cc = 0; cc < 4; ++cc)
      pp[mr * 64 + s4 * 16 + 4 * il + cc] = facc[cc] + sRed[s4 * 256 + (4 * il + cc) * 16 + mr];
  }
}

// ================= reduce: out = part(chh=0) + part(chh=1) + bias =================
__global__ __launch_bounds__(256)
void reduce_k(const float* __restrict__ part, const float* __restrict__ bf,
              float* __restrict__ out)
{
  const int e = blockIdx.x * 256 + threadIdx.x;     // 262144 outputs
  const int o = e & 63, g = (e >> 6) & 7, bcg = e >> 9;
  const int bcT = bcg >> 4, bcl = bcg & 15;
  const float s = bf[g * 64 + o]
      + part[((size_t)(0 * 8 + g) * 32 + bcT) * 1024 + bcl * 64 + o]
      + part[((size_t)(1 * 8 + g) * 32 + bcT) * 1024 + bcl * 64 + o];
  out[e] = s;
}

} // namespace

extern "C" void kernel_launch(void* const* d_in, const int* in_sizes, int n_in,
                              void* d_out, int out_size, void* d_ws, size_t ws_size,
                              hipStream_t stream) {
  const float* x   = (const float*)d_in[0];
  const float* xm  = (const float*)d_in[1];
  const float* Wd  = (const float*)d_in[2];
  const float* bd  = (const float*)d_in[3];
  const float* Wm  = (const float*)d_in[4];
  const float* bm  = (const float*)d_in[5];
  const float* Gd  = (const float*)d_in[6];
  const float* bgd = (const float*)d_in[7];
  const float* Gm  = (const float*)d_in[8];
  const float* bgm = (const float*)d_in[9];
  const float* Gh  = (const float*)d_in[10];
  const float* bgh = (const float*)d_in[11];
  const float* Fw  = (const float*)d_in[12];
  const float* bf  = (const float*)d_in[13];
  float* outp = (float*)d_out;

  ushort* feat = (ushort*)((char*)d_ws + FEAT_OFF);
  ushort* FwT  = (ushort*)((char*)d_ws + FWT_OFF);
  ushort* cA   = (ushort*)((char*)d_ws + CA_OFF);
  ushort* GT   = (ushort*)((char*)d_ws + GT_OFF);
  float*  part = (float*)((char*)d_ws + PART_OFF);

  prep_k<<<dim3(1504), dim3(512), 0, stream>>>(
      x, xm, Fw, Gd, bgd, Gm, bgm, Gh, bgh, Wd, bd, Wm, bm, feat, FwT, GT, cA);
  fused_v7<<<dim3(512), dim3(512), 0, stream>>>(feat, FwT, cA, GT, part);
  reduce_k<<<dim3(1024), dim3(256), 0, stream>>>(part, bf, outp);
}

// Round 9
// 60.366 us; speedup vs baseline: 1.6331x; 1.6331x over previous
//
#include <hip/hip_runtime.h>
#include <hip/hip_bf16.h>

namespace {

typedef __attribute__((ext_vector_type(8))) short bh8;   // 8 bf16 = 4 VGPR MFMA A/B frag
typedef __attribute__((ext_vector_type(4))) short sh4;   // 4 bf16 (8B)
typedef __attribute__((ext_vector_type(4))) float fx4;

constexpr int Rn = 96, Cn = 64, CINn = 8, COUTn = 64;
constexpr int NPOS = 8 * 96 * 64 * 8;       // 393216 (b,r,c,g) positions
constexpr int PPG  = 8 * 96 * 64;           // 49152 (b,r,c) per g
// ws layout (bytes)
constexpr size_t FEAT_OFF = 0;                                // feat bf16x8, G-MAJOR [g][pb]: 6.29 MB
constexpr size_t FWT_OFF  = (size_t)NPOS * 16;                // FwT bf16 [g][o][r][i]: 6.29 MB
constexpr size_t CA_OFF   = FWT_OFF + (size_t)NPOS * 16;      // convA bf16 [g][co][64]: 64 KB
constexpr size_t GT_OFF   = CA_OFF + 65536;                   // gate table bf16 [g*128+o2][80]: 160 KB
constexpr size_t PART_OFF = GT_OFF + 163840;                  // partials f32 [16][32][1024]: 2 MB

__device__ inline ushort f2b(float f) {
  __hip_bfloat16 h = __float2bfloat16(f);
  return __builtin_bit_cast(ushort, h);
}
__device__ inline float b2f(ushort u) {
  return __builtin_bit_cast(float, (unsigned)u << 16);
}
// swizzled byte offset into a [16 bc][8 rr][64 i] bf16 buffer (128B rows, 16KB)
__device__ inline int swz8(int bc, int rr, int ib) {
  return (bc * 1024 + rr * 128 + ib) ^ (((rr + bc) & 7) << 4);
}

#define MFMA16(a, b, c) __builtin_amdgcn_mfma_f32_16x16x32_bf16((a), (b), (c), 0, 0, 0)

// ================= prep_k: feat pack (g-major) + FwT transpose + tables =================
__global__ __launch_bounds__(512)
void prep_k(const float* __restrict__ x, const float* __restrict__ xm,
            const float* __restrict__ Fw,
            const float* __restrict__ Gd, const float* __restrict__ bgd,
            const float* __restrict__ Gm, const float* __restrict__ bgm,
            const float* __restrict__ Gh, const float* __restrict__ bgh,
            const float* __restrict__ Wd, const float* __restrict__ bd,
            const float* __restrict__ Wm, const float* __restrict__ bm,
            ushort* __restrict__ feat, ushort* __restrict__ FwT,
            ushort* __restrict__ GT, ushort* __restrict__ cA)
{
  __shared__ float tile[64 * 97];
  const int bid = blockIdx.x, t = threadIdx.x;
  if (bid < 768) {
    const int pos = bid * 512 + t;
    const float xs = x[pos];
    const fx4 m = *(const fx4*)(xm + (size_t)pos * 4);
    bh8 o;
    o[0] = (short)f2b(xs);
    o[1] = (short)f2b(m[0]); o[2] = (short)f2b(m[1]);
    o[3] = (short)f2b(m[2]); o[4] = (short)f2b(m[3]);
    o[5] = (short)0x3F80; o[6] = 0; o[7] = 0;
    const int g = pos & 7, pb = pos >> 3;
    *(bh8*)(feat + ((size_t)g * PPG + pb) * 8) = o;
  } else if (bid < 1280) {
    const int go = bid - 768;
    const float* src = Fw + (size_t)go * 6144;
    ushort* dst = FwT + (size_t)go * 6144;
#pragma unroll
    for (int it = 0; it < 12; ++it) {
      const int idx = t + it * 512;
      tile[(idx / 96) * 97 + (idx % 96)] = src[idx];
    }
    __syncthreads();
#pragma unroll
    for (int it = 0; it < 12; ++it) {
      const int idx = t + it * 512;
      const int r = idx >> 6, i = idx & 63;
      dst[idx] = f2b(tile[i * 97 + r]);
    }
  } else if (bid < 1440) {
    const int idx = (bid - 1280) * 512 + t;   // 81920
    const int ro = idx / 80, c = idx - ro * 80;
    float v = 0.f;
    if (c < 64)       v = Gh[(size_t)ro * 64 + c];
    else if (c == 64) v = Gd[ro];
    else if (c <= 68) v = Gm[(size_t)ro * 4 + (c - 65)];
    else if (c == 69) v = bgd[ro] + bgm[ro] + bgh[ro];
    GT[idx] = f2b(v);
  } else {
    const int e = (bid - 1440) * 512 + t;     // 32768
    const int g = e >> 12, co = (e >> 6) & 63, k = e & 63;
    const int tap = k >> 3, tch = k & 7;
    float v = 0.f;
    if (tch == 0)      v = Wd[(g * 64 + co) * 8 + tap];
    else if (tch <= 4) v = Wm[((g * 64 + co) * 4 + (tch - 1)) * 8 + tap];
    else if (tch == 5 && tap == 0) v = bd[g * 64 + co] + bm[g * 64 + co];
    cA[e] = f2b(v);
  }
}

// ================= main: persistent block, 6 chunks, A-tables staged in LDS =================
__global__ __launch_bounds__(512, 4)
void fused_v8(const ushort* __restrict__ feat, const ushort* __restrict__ FwT,
              const ushort* __restrict__ cA, const ushort* __restrict__ GT,
              float* __restrict__ part)
{
  __shared__ __align__(16) ushort sTabA[8 * 64 * 8];    //  8 KB conv A frags  [s*2+hh][lane][8]
  __shared__ __align__(16) ushort sTabG[24 * 64 * 8];   // 24 KB gate A frags  [hw*12+f][lane][8]
  __shared__ __align__(16) char sHid[16384];            // [16bc][8rr][64i] bf16, swizzled
  __shared__ __align__(16) char sGat[16384];            // gated hid, same layout
  __shared__ float sRed[4 * 256];                       // fc hf-reduce

  const int t    = threadIdx.x;
  const int lane = t & 63;
  const int w    = t >> 6;
  const int il   = lane >> 4;
  const int mr   = lane & 15;
  const int bid  = blockIdx.x;
  const int g    = bid & 7;                    // XCD-affine (512 % 8 == 0, bijective)
  const int bcT  = (bid >> 3) & 31;
  const int chh  = bid >> 8;                   // 0..1 -> rows chh*48 .. chh*48+47
  const ushort* fg = feat + (size_t)g * PPG * 8;
  const int hw   = w & 1;
  const int s4   = w & 3, hf = w >> 2;

  // ---- conv geometry (fixed per thread): pos = w*16+mr -> (bcl, rr) ----
  const int pglob = w * 16 + mr;
  const int cbcl = pglob >> 3, crr = pglob & 7;
  const int cbcg = bcT * 16 + cbcl;
  const int cbb = cbcg >> 6, ccc = cbcg & 63;

  // ---- stage A-tables to LDS, fragment-ordered [frag][lane] (waves 0..2 only) ----
  if (w < 2) {
    const ushort* gtg = GT + (size_t)g * 128 * 80;
    const int xo = (il == 0) ? 64 : 72;          // il>0 lanes get the zero frag
#pragma unroll
    for (int ss = 0; ss < 2; ++ss) {
      const int s = 2 * w + ss;                  // this wave's hw == w
      const ushort* bs = gtg + (s * 16 + mr) * 80;
      const ushort* bt = gtg + (64 + s * 16 + mr) * 80;
      *(bh8*)&sTabA[0] = *(bh8*)&sTabA[0];       // no-op placeholder removed by compiler
      *(bh8*)&sTabG[((w * 12 + ss * 6 + 0) * 64 + lane) * 8] = *(const bh8*)(bs + 8 * il);
      *(bh8*)&sTabG[((w * 12 + ss * 6 + 1) * 64 + lane) * 8] = *(const bh8*)(bs + 32 + 8 * il);
      *(bh8*)&sTabG[((w * 12 + ss * 6 + 2) * 64 + lane) * 8] = *(const bh8*)(bs + xo);
      *(bh8*)&sTabG[((w * 12 + ss * 6 + 3) * 64 + lane) * 8] = *(const bh8*)(bt + 8 * il);
      *(bh8*)&sTabG[((w * 12 + ss * 6 + 4) * 64 + lane) * 8] = *(const bh8*)(bt + 32 + 8 * il);
      *(bh8*)&sTabG[((w * 12 + ss * 6 + 5) * 64 + lane) * 8] = *(const bh8*)(bt + xo);
    }
  } else if (w == 2) {
    const ushort* cAg = cA + g * 4096;
#pragma unroll
    for (int s = 0; s < 4; ++s)
#pragma unroll
      for (int hh = 0; hh < 2; ++hh)
        *(bh8*)&sTabA[((s * 2 + hh) * 64 + lane) * 8] =
            *(const bh8*)(cAg + (s * 16 + mr) * 64 + hh * 32 + 8 * il);
  }

  const ushort* fbase = FwT + ((size_t)(g * 64 + s4 * 16 + mr) * 96) * 64 + 32 * hf + 8 * il;
  fx4 facc = {0.f, 0.f, 0.f, 0.f};
  const bh8 zpad = {0, 0, 0, 0, 0, (short)0x3F80, 0, 0};

  // ---- prefetch chunk 0 conv inputs (clamped address; pad-select at use) ----
  bh8 b0, b1;
  {
    const int r0 = chh * 48;
    const int q0 = r0 + crr - 8 + il;
    const int q1 = q0 + 4;
    b0 = *(const bh8*)(fg + (size_t)((cbb * 96 + (q0 > 0 ? q0 : 0)) * 64 + ccc) * 8);
    b1 = *(const bh8*)(fg + (size_t)((cbb * 96 + (q1 > 0 ? q1 : 0)) * 64 + ccc) * 8);
  }
  __syncthreads();   // B0: tables staged

#pragma unroll
  for (int k = 0; k < 6; ++k) {
    const int r0 = chh * 48 + k * 8;

    // ---------- conv phase ----------
    if (k == 0 && chh == 0) {              // only chunk 0 has negative taps
      const int q0 = crr - 8 + il;
      if (q0 < 0) b0 = zpad;
      if (q0 + 4 < 0) b1 = zpad;
    }
#pragma unroll
    for (int s = 0; s < 4; ++s) {
      const bh8 aC0 = *(const bh8*)&sTabA[((s * 2 + 0) * 64 + lane) * 8];
      const bh8 aC1 = *(const bh8*)&sTabA[((s * 2 + 1) * 64 + lane) * 8];
      fx4 a = {0.f, 0.f, 0.f, 0.f};
      a = MFMA16(aC0, b0, a);
      a = MFMA16(aC1, b1, a);
      sh4 o4;
#pragma unroll
      for (int cc = 0; cc < 4; ++cc) o4[cc] = (short)f2b(a[cc]);
      *(sh4*)(sHid + swz8(cbcl, crr, s * 32 + il * 8)) = o4;
    }
    // prefetch next chunk's conv inputs (q >= 0 always for k>=1 rows)
    if (k < 5) {
      const int qn0 = r0 + crr + il;       // = (r0+8) + crr - 8 + il
      b0 = *(const bh8*)(fg + (size_t)((cbb * 96 + qn0) * 64 + ccc) * 8);
      b1 = *(const bh8*)(fg + (size_t)((cbb * 96 + qn0 + 4) * 64 + ccc) * 8);
    }
    __syncthreads();   // B1: sHid ready

    // ---------- gate phase: pair p=w>>1 owns nt {2p,2p+1}; hw owns s {2hw,2hw+1} ----------
    {
      bh8 gAr[12];
#pragma unroll
      for (int f = 0; f < 12; ++f)
        gAr[f] = *(const bh8*)&sTabG[((hw * 12 + f) * 64 + lane) * 8];

      bh8 bx[2];
#pragma unroll
      for (int nti = 0; nti < 2; ++nti) {
        const int nt = (w >> 1) * 2 + nti;
        const int pg = nt * 16 + mr;
        const int bcl = pg >> 3, rr = pg & 7;
        const int bcg = bcT * 16 + bcl;
        const int bb = bcg >> 6, cc_ = bcg & 63;
        bx[nti] = *(const bh8*)(fg + (size_t)((bb * 96 + r0 + rr) * 64 + cc_) * 8);
      }
#pragma unroll
      for (int nti = 0; nti < 2; ++nti) {
        const int nt = (w >> 1) * 2 + nti;
        const int pg = nt * 16 + mr;
        const int bcl = pg >> 3, rr = pg & 7;
        const bh8 h0 = *(const bh8*)(sHid + swz8(bcl, rr, 16 * il));
        const bh8 h1 = *(const bh8*)(sHid + swz8(bcl, rr, 64 + 16 * il));
#pragma unroll
        for (int ss = 0; ss < 2; ++ss) {
          const int s = 2 * hw + ss;
          fx4 aS = {0.f,0.f,0.f,0.f}, aT = {0.f,0.f,0.f,0.f};
          aS = MFMA16(gAr[ss * 6 + 0], h0, aS);
          aS = MFMA16(gAr[ss * 6 + 1], h1, aS);
          aT = MFMA16(gAr[ss * 6 + 3], h0, aT);
          aT = MFMA16(gAr[ss * 6 + 4], h1, aT);
          aS = MFMA16(gAr[ss * 6 + 2], bx[nti], aS);
          aT = MFMA16(gAr[ss * 6 + 5], bx[nti], aT);
          const sh4 h4 = *(const sh4*)(sHid + swz8(bcl, rr, s * 32 + il * 8));
          sh4 o4;
#pragma unroll
          for (int cc = 0; cc < 4; ++cc) {
            const float sig = 1.f / (1.f + __expf(-aS[cc]));
            const float th  = 1.f - 2.f / (1.f + __expf(2.f * aT[cc]));
            const float h   = fmaf(b2f((ushort)h4[cc]), sig, (1.f - sig) * th);
            o4[cc] = (short)f2b(h);
          }
          *(sh4*)(sGat + swz8(bcl, rr, s * 32 + il * 8)) = o4;
        }
      }
    }
    __syncthreads();   // B2: sGat ready

    // ---------- fc phase: accumulate into facc ----------
    {
      const ushort* fb = fbase + (size_t)r0 * 64;
#pragma unroll
      for (int f = 0; f < 8; ++f) {
        const bh8 aF = *(const bh8*)(fb + f * 64);
        const bh8 bF = *(const bh8*)(sGat + swz8(mr, f, 64 * hf + 16 * il));
        facc = MFMA16(aF, bF, facc);
      }
    }
  }

  // ---- hf-reduce + write partial (2 slices per output) ----
  if (hf == 1) {
#pragma unroll
    for (int cc = 0; cc < 4; ++cc)
      sRed[s4 * 256 + (4 * il + cc) * 16 + mr] = facc[cc];
  }
  __syncthreads();
  if (hf == 0) {
    float* pp = part + ((size_t)(chh * 8 + g) * 32 + bcT) * 1024;
#pragma unroll
    for (int cc = 0; cc < 4; ++cc)
      pp[mr * 64 + s4 * 16 + 4 * il + cc] = facc[cc] + sRed[s4 * 256 + (4 * il + cc) * 16 + mr];
  }
}

// ================= reduce: out = part(chh=0) + part(chh=1) + bias =================
__global__ __launch_bounds__(256)
void reduce_k(const float* __restrict__ part, const float* __restrict__ bf,
              float* __restrict__ out)
{
  const int e = blockIdx.x * 256 + threadIdx.x;     // 262144 outputs
  const int o = e & 63, g = (e >> 6) & 7, bcg = e >> 9;
  const int bcT = bcg >> 4, bcl = bcg & 15;
  const float s = bf[g * 64 + o]
      + part[((size_t)(0 * 8 + g) * 32 + bcT) * 1024 + bcl * 64 + o]
      + part[((size_t)(1 * 8 + g) * 32 + bcT) * 1024 + bcl * 64 + o];
  out[e] = s;
}

} // namespace

extern "C" void kernel_launch(void* const* d_in, const int* in_sizes, int n_in,
                              void* d_out, int out_size, void* d_ws, size_t ws_size,
                              hipStream_t stream) {
  const float* x   = (const float*)d_in[0];
  const float* xm  = (const float*)d_in[1];
  const float* Wd  = (const float*)d_in[2];
  const float* bd  = (const float*)d_in[3];
  const float* Wm  = (const float*)d_in[4];
  const float* bm  = (const float*)d_in[5];
  const float* Gd  = (const float*)d_in[6];
  const float* bgd = (const float*)d_in[7];
  const float* Gm  = (const float*)d_in[8];
  const float* bgm = (const float*)d_in[9];
  const float* Gh  = (const float*)d_in[10];
  const float* bgh = (const float*)d_in[11];
  const float* Fw  = (const float*)d_in[12];
  const float* bf  = (const float*)d_in[13];
  float* outp = (float*)d_out;

  ushort* feat = (ushort*)((char*)d_ws + FEAT_OFF);
  ushort* FwT  = (ushort*)((char*)d_ws + FWT_OFF);
  ushort* cA   = (ushort*)((char*)d_ws + CA_OFF);
  ushort* GT   = (ushort*)((char*)d_ws + GT_OFF);
  float*  part = (float*)((char*)d_ws + PART_OFF);

  prep_k<<<dim3(1504), dim3(512), 0, stream>>>(
      x, xm, Fw, Gd, bgd, Gm, bgm, Gh, bgh, Wd, bd, Wm, bm, feat, FwT, GT, cA);
  fused_v8<<<dim3(512), dim3(512), 0, stream>>>(feat, FwT, cA, GT, part);
  reduce_k<<<dim3(1024), dim3(256), 0, stream>>>(part, bf, outp);
}

// Round 10
// 55.999 us; speedup vs baseline: 1.7604x; 1.0780x over previous
//
#include <hip/hip_runtime.h>
#include <hip/hip_bf16.h>

namespace {

typedef __attribute__((ext_vector_type(8))) short bh8;   // 8 bf16 = 4 VGPR MFMA A/B frag
typedef __attribute__((ext_vector_type(4))) short sh4;   // 4 bf16 (8B)
typedef __attribute__((ext_vector_type(4))) float fx4;

constexpr int Rn = 96, Cn = 64, CINn = 8, COUTn = 64;
constexpr int NPOS = 8 * 96 * 64 * 8;       // 393216 (b,r,c,g) positions
constexpr int PPG  = 8 * 96 * 64;           // 49152 (b,r,c) per g
// ws layout (bytes)
constexpr size_t FEAT_OFF = 0;                                // feat bf16x8, G-MAJOR [g][pb]: 6.29 MB
constexpr size_t FWT_OFF  = (size_t)NPOS * 16;                // FwT bf16 [g][o][r][i]: 6.29 MB
constexpr size_t CA_OFF   = FWT_OFF + (size_t)NPOS * 16;      // convA bf16 [g][co][64]: 64 KB
constexpr size_t GT_OFF   = CA_OFF + 65536;                   // gate table bf16 [g*128+o2][80]: 160 KB
constexpr size_t PART_OFF = GT_OFF + 163840;                  // partials f32 [16][32][1024]: 2 MB

__device__ inline ushort f2b(float f) {
  __hip_bfloat16 h = __float2bfloat16(f);
  return __builtin_bit_cast(ushort, h);
}
// swizzled byte offset into a [16 bc][8 rr][64 i] bf16 buffer (128B rows, 16KB)
__device__ inline int swz8(int bc, int rr, int ib) {
  return (bc * 1024 + rr * 128 + ib) ^ (((rr + bc) & 7) << 4);
}

#define MFMA16(a, b, c) __builtin_amdgcn_mfma_f32_16x16x32_bf16((a), (b), (c), 0, 0, 0)

// ================= prep_k: feat pack (g-major) + FwT transpose + tables =================
__global__ __launch_bounds__(512)
void prep_k(const float* __restrict__ x, const float* __restrict__ xm,
            const float* __restrict__ Fw,
            const float* __restrict__ Gd, const float* __restrict__ bgd,
            const float* __restrict__ Gm, const float* __restrict__ bgm,
            const float* __restrict__ Gh, const float* __restrict__ bgh,
            const float* __restrict__ Wd, const float* __restrict__ bd,
            const float* __restrict__ Wm, const float* __restrict__ bm,
            ushort* __restrict__ feat, ushort* __restrict__ FwT,
            ushort* __restrict__ GT, ushort* __restrict__ cA)
{
  __shared__ float tile[64 * 97];
  const int bid = blockIdx.x, t = threadIdx.x;
  if (bid < 768) {
    const int pos = bid * 512 + t;
    const float xs = x[pos];
    const fx4 m = *(const fx4*)(xm + (size_t)pos * 4);
    bh8 o;
    o[0] = (short)f2b(xs);
    o[1] = (short)f2b(m[0]); o[2] = (short)f2b(m[1]);
    o[3] = (short)f2b(m[2]); o[4] = (short)f2b(m[3]);
    o[5] = (short)0x3F80; o[6] = 0; o[7] = 0;
    const int g = pos & 7, pb = pos >> 3;
    *(bh8*)(feat + ((size_t)g * PPG + pb) * 8) = o;
  } else if (bid < 1280) {
    const int go = bid - 768;
    const float* src = Fw + (size_t)go * 6144;
    ushort* dst = FwT + (size_t)go * 6144;
#pragma unroll
    for (int it = 0; it < 12; ++it) {
      const int idx = t + it * 512;
      tile[(idx / 96) * 97 + (idx % 96)] = src[idx];
    }
    __syncthreads();
#pragma unroll
    for (int it = 0; it < 12; ++it) {
      const int idx = t + it * 512;
      const int r = idx >> 6, i = idx & 63;
      dst[idx] = f2b(tile[i * 97 + r]);
    }
  } else if (bid < 1440) {
    const int idx = (bid - 1280) * 512 + t;   // 81920
    const int ro = idx / 80, c = idx - ro * 80;
    float v = 0.f;
    if (c < 64)       v = Gh[(size_t)ro * 64 + c];
    else if (c == 64) v = Gd[ro];
    else if (c <= 68) v = Gm[(size_t)ro * 4 + (c - 65)];
    else if (c == 69) v = bgd[ro] + bgm[ro] + bgh[ro];
    GT[idx] = f2b(v);
  } else {
    const int e = (bid - 1440) * 512 + t;     // 32768
    const int g = e >> 12, co = (e >> 6) & 63, k = e & 63;
    const int tap = k >> 3, tch = k & 7;
    float v = 0.f;
    if (tch == 0)      v = Wd[(g * 64 + co) * 8 + tap];
    else if (tch <= 4) v = Wm[((g * 64 + co) * 4 + (tch - 1)) * 8 + tap];
    else if (tch == 5 && tap == 0) v = bd[g * 64 + co] + bm[g * 64 + co];
    cA[e] = f2b(v);
  }
}

// ================= main: intra-wave conv->gate, 1 barrier/chunk, dbuf sGat =================
__global__ __launch_bounds__(512, 2)
void fused_v9(const ushort* __restrict__ feat, const ushort* __restrict__ FwT,
              const ushort* __restrict__ cA, const ushort* __restrict__ GT,
              float* __restrict__ part)
{
  __shared__ __align__(16) ushort sTabG[8 * 3 * 64 * 8];  // 24 KB gate A frags [sub*3+f][lane][8]
  __shared__ __align__(16) char sHid[16384];              // per-wave-private hid rows
  __shared__ __align__(16) char sGat[2][16384];           // gated hid, double-buffered
  __shared__ float sRed[4 * 256];                         // fc hf-reduce

  const int t    = threadIdx.x;
  const int lane = t & 63;
  const int w    = t >> 6;
  const int il   = lane >> 4;
  const int mr   = lane & 15;
  const int bid  = blockIdx.x;
  const int g    = bid & 7;                    // XCD-affine (512 % 8 == 0, bijective)
  const int bcT  = (bid >> 3) & 31;
  const int chh  = bid >> 8;                   // 0..1 -> rows chh*48 .. chh*48+47
  const ushort* fg = feat + (size_t)g * PPG * 8;
  const int s4   = w & 3, hf = w >> 2;

  // ---- this wave's 16 positions: pglob = w*16+mr ----
  const int pglob = w * 16 + mr;
  const int cbcl = pglob >> 3, crr = pglob & 7;
  const int cbcg = bcT * 16 + cbcl;
  const int cbb = cbcg >> 6, ccc = cbcg & 63;
  const size_t prow = (size_t)(cbb * 96) * 64 + ccc;    // feat row index base (x8 ushorts)

  // ---- stage gate A-table: wave w stages o2-subtile sub = w (rows w*16+mr) ----
  {
    const ushort* brow = GT + ((size_t)g * 128 + w * 16 + mr) * 80;
    const int xo = (il == 0) ? 64 : 72;          // il>0 lanes get the zero frag
    *(bh8*)&sTabG[((w * 3 + 0) * 64 + lane) * 8] = *(const bh8*)(brow + 8 * il);
    *(bh8*)&sTabG[((w * 3 + 1) * 64 + lane) * 8] = *(const bh8*)(brow + 32 + 8 * il);
    *(bh8*)&sTabG[((w * 3 + 2) * 64 + lane) * 8] = *(const bh8*)(brow + xo);
  }

  // ---- conv A-frags in registers (32 VGPR) ----
  bh8 aC[4][2];
  {
    const ushort* cAg = cA + g * 4096;
#pragma unroll
    for (int s = 0; s < 4; ++s)
#pragma unroll
      for (int hh = 0; hh < 2; ++hh)
        aC[s][hh] = *(const bh8*)(cAg + (s * 16 + mr) * 64 + hh * 32 + 8 * il);
  }

  const ushort* fbase = FwT + ((size_t)(g * 64 + s4 * 16 + mr) * 96) * 64 + 32 * hf + 8 * il;
  fx4 facc = {0.f, 0.f, 0.f, 0.f};
  const bh8 zpad = {0, 0, 0, 0, 0, (short)0x3F80, 0, 0};

  // ---- prefetch chunk-0 conv inputs + gate bx ----
  bh8 b0, b1, bx;
  {
    const int r0 = chh * 48;
    const int q0 = r0 + crr - 8 + il;
    const int q1 = q0 + 4;
    b0 = *(const bh8*)(fg + (prow + (size_t)(q0 > 0 ? q0 : 0) * 64) * 8);
    b1 = *(const bh8*)(fg + (prow + (size_t)(q1 > 0 ? q1 : 0) * 64) * 8);
    bx = *(const bh8*)(fg + (prow + (size_t)(r0 + crr) * 64) * 8);
  }
  __syncthreads();   // B0: sTabG staged

#pragma unroll 1
  for (int k = 0; k < 6; ++k) {
    const int r0 = chh * 48 + k * 8;

    // ---------- conv (intra-wave): hid0 for own 16 positions, acc kept in f32 ----------
    if (k == 0 && chh == 0) {
      const int q0 = crr - 8 + il;
      if (q0 < 0) b0 = zpad;
      if (q0 + 4 < 0) b1 = zpad;
    }
    fx4 ah[4];
#pragma unroll
    for (int s = 0; s < 4; ++s) {
      fx4 a = {0.f, 0.f, 0.f, 0.f};
      a = MFMA16(aC[s][0], b0, a);
      a = MFMA16(aC[s][1], b1, a);
      ah[s] = a;
      sh4 o4;
#pragma unroll
      for (int cc = 0; cc < 4; ++cc) o4[cc] = (short)f2b(a[cc]);
      *(sh4*)(sHid + swz8(cbcl, crr, s * 32 + il * 8)) = o4;
    }
    // prefetch next chunk's inputs (rows >= 40, no pad)
    bh8 b0n = b0, b1n = b1, bxn = bx;
    if (k < 5) {
      const int qn0 = r0 + crr + il;
      b0n = *(const bh8*)(fg + (prow + (size_t)qn0 * 64) * 8);
      b1n = *(const bh8*)(fg + (prow + (size_t)(qn0 + 4) * 64) * 8);
      bxn = *(const bh8*)(fg + (prow + (size_t)(r0 + 8 + crr) * 64) * 8);
    }

    // ---------- gate (intra-wave): own positions, all 8 o2-subtiles ----------
    {
      const bh8 h0 = *(const bh8*)(sHid + swz8(cbcl, crr, 16 * il));
      const bh8 h1 = *(const bh8*)(sHid + swz8(cbcl, crr, 64 + 16 * il));
      char* gbuf = sGat[k & 1];
#pragma unroll
      for (int s = 0; s < 4; ++s) {
        fx4 accS = {0.f,0.f,0.f,0.f}, accT = {0.f,0.f,0.f,0.f};
        {
          const bh8 a0 = *(const bh8*)&sTabG[((s * 3 + 0) * 64 + lane) * 8];
          const bh8 a1 = *(const bh8*)&sTabG[((s * 3 + 1) * 64 + lane) * 8];
          const bh8 a2 = *(const bh8*)&sTabG[((s * 3 + 2) * 64 + lane) * 8];
          accS = MFMA16(a0, h0, accS);
          accS = MFMA16(a1, h1, accS);
          accS = MFMA16(a2, bx, accS);
        }
        {
          const bh8 a0 = *(const bh8*)&sTabG[(((s + 4) * 3 + 0) * 64 + lane) * 8];
          const bh8 a1 = *(const bh8*)&sTabG[(((s + 4) * 3 + 1) * 64 + lane) * 8];
          const bh8 a2 = *(const bh8*)&sTabG[(((s + 4) * 3 + 2) * 64 + lane) * 8];
          accT = MFMA16(a0, h0, accT);
          accT = MFMA16(a1, h1, accT);
          accT = MFMA16(a2, bx, accT);
        }
        sh4 o4;
#pragma unroll
        for (int cc = 0; cc < 4; ++cc) {
          const float sig = 1.f / (1.f + __expf(-accS[cc]));
          const float th  = 1.f - 2.f / (1.f + __expf(2.f * accT[cc]));
          const float h   = fmaf(sig, ah[s][cc] - th, th);   // h0*sig + (1-sig)*th
          o4[cc] = (short)f2b(h);
        }
        *(sh4*)(gbuf + swz8(cbcl, crr, s * 32 + il * 8)) = o4;
      }
    }
    __syncthreads();   // B(k): gbuf complete; also fences fc(k-1) reads vs gate(k+1) writes

    // ---------- fc: cross-wave read of gbuf, accumulate into facc ----------
    {
      const char* gbuf = sGat[k & 1];
      const ushort* fb = fbase + (size_t)r0 * 64;
#pragma unroll
      for (int f = 0; f < 8; ++f) {
        const bh8 aF = *(const bh8*)(fb + f * 64);
        const bh8 bF = *(const bh8*)(gbuf + swz8(mr, f, 64 * hf + 16 * il));
        facc = MFMA16(aF, bF, facc);
      }
    }
    b0 = b0n; b1 = b1n; bx = bxn;
  }

  // ---- hf-reduce + write partial (2 slices per output) ----
  if (hf == 1) {
#pragma unroll
    for (int cc = 0; cc < 4; ++cc)
      sRed[s4 * 256 + (4 * il + cc) * 16 + mr] = facc[cc];
  }
  __syncthreads();
  if (hf == 0) {
    float* pp = part + ((size_t)(chh * 8 + g) * 32 + bcT) * 1024;
#pragma unroll
    for (int cc = 0; cc < 4; ++cc)
      pp[mr * 64 + s4 * 16 + 4 * il + cc] = facc[cc] + sRed[s4 * 256 + (4 * il + cc) * 16 + mr];
  }
}

// ================= reduce: out = part(chh=0) + part(chh=1) + bias =================
__global__ __launch_bounds__(256)
void reduce_k(const float* __restrict__ part, const float* __restrict__ bf,
              float* __restrict__ out)
{
  const int e = blockIdx.x * 256 + threadIdx.x;     // 262144 outputs
  const int o = e & 63, g = (e >> 6) & 7, bcg = e >> 9;
  const int bcT = bcg >> 4, bcl = bcg & 15;
  const float s = bf[g * 64 + o]
      + part[((size_t)(0 * 8 + g) * 32 + bcT) * 1024 + bcl * 64 + o]
      + part[((size_t)(1 * 8 + g) * 32 + bcT) * 1024 + bcl * 64 + o];
  out[e] = s;
}

} // namespace

extern "C" void kernel_launch(void* const* d_in, const int* in_sizes, int n_in,
                              void* d_out, int out_size, void* d_ws, size_t ws_size,
                              hipStream_t stream) {
  const float* x   = (const float*)d_in[0];
  const float* xm  = (const float*)d_in[1];
  const float* Wd  = (const float*)d_in[2];
  const float* bd  = (const float*)d_in[3];
  const float* Wm  = (const float*)d_in[4];
  const float* bm  = (const float*)d_in[5];
  const float* Gd  = (const float*)d_in[6];
  const float* bgd = (const float*)d_in[7];
  const float* Gm  = (const float*)d_in[8];
  const float* bgm = (const float*)d_in[9];
  const float* Gh  = (const float*)d_in[10];
  const float* bgh = (const float*)d_in[11];
  const float* Fw  = (const float*)d_in[12];
  const float* bf  = (const float*)d_in[13];
  float* outp = (float*)d_out;

  ushort* feat = (ushort*)((char*)d_ws + FEAT_OFF);
  ushort* FwT  = (ushort*)((char*)d_ws + FWT_OFF);
  ushort* cA   = (ushort*)((char*)d_ws + CA_OFF);
  ushort* GT   = (ushort*)((char*)d_ws + GT_OFF);
  float*  part = (float*)((char*)d_ws + PART_OFF);

  prep_k<<<dim3(1504), dim3(512), 0, stream>>>(
      x, xm, Fw, Gd, bgd, Gm, bgm, Gh, bgh, Wd, bd, Wm, bm, feat, FwT, GT, cA);
  fused_v9<<<dim3(512), dim3(512), 0, stream>>>(feat, FwT, cA, GT, part);
  reduce_k<<<dim3(1024), dim3(256), 0, stream>>>(part, bf, outp);
}